// Round 1
// baseline (566.998 us; speedup 1.0000x reference)
//
#include <hip/hip_runtime.h>
#include <hip/hip_cooperative_groups.h>

#define BB   64
#define CC   64
#define NSP  12544     // 112*112
#define NSP4 3136      // NSP/4
#define BC   (BB*CC)   // 4096
#define KCL  8
#define NBLK 1024      // 4 blocks/CU -> cooperative co-residency guaranteed
#define SPB  4         // slices per block (NBLK*SPB == BC)

typedef float f32x4 __attribute__((ext_vector_type(4)));

// ---------------- Fused cooperative kernel ----------------
// Block j owns channel c = j&63 and samples b = 4*(j>>6) .. +3.
// Phase 1: per-slice sum/sumsq (identical accumulation order to the verified
//          3-kernel version -> bitwise-same s1/s2).
// grid.sync(): device-wide barrier (replaces 2 kernel boundaries + the
//          1-block stats kernel).
// Phase 2: per-block redundant cluster stats for channel c only (cheap).
// Phase 3: out = x*A + Bias on the same 4 slices (same CU/XCD -> L2/L3 hot),
//          non-temporal stores.
__global__ __launch_bounds__(256, 4) void fused_kernel(
    const f32x4* __restrict__ x, const float* __restrict__ cluster_map,
    const float* __restrict__ lmda, f32x4* __restrict__ out,
    float* __restrict__ s1g, float* __restrict__ s2g)
{
    const int j = blockIdx.x;
    const int t = threadIdx.x;
    const int c = j & 63;
    const int bbase = (j >> 6) * SPB;

    __shared__ float w1[4], w2[4];

    // ---- Phase 1: reduce my 4 slices ----
    for (int sb = 0; sb < SPB; ++sb) {
        const int b = bbase + sb;
        const f32x4* p = x + (size_t)(b * CC + c) * NSP4;
        float a1 = 0.0f, a2 = 0.0f;
        for (int i = t; i < NSP4; i += 256) {
            f32x4 v = p[i];
            a1 += v.x + v.y + v.z + v.w;
            a2 += v.x * v.x + v.y * v.y + v.z * v.z + v.w * v.w;
        }
        for (int off = 32; off > 0; off >>= 1) {
            a1 += __shfl_down(a1, off, 64);
            a2 += __shfl_down(a2, off, 64);
        }
        const int wid = t >> 6;
        if ((t & 63) == 0) { w1[wid] = a1; w2[wid] = a2; }
        __syncthreads();
        if (t == 0) {
            s1g[b * CC + c] = (w1[0] + w1[1]) + (w1[2] + w1[3]);
            s2g[b * CC + c] = (w2[0] + w2[1]) + (w2[2] + w2[3]);
        }
        __syncthreads();   // w1/w2 reused next iteration
    }

    __threadfence();   // belt-and-braces: make s1g/s2g visible before barrier
    cooperative_groups::this_grid().sync();

    // ---- Phase 2: stats for channel c (redundant per block, tiny) ----
    __shared__ int   cid[BB];
    __shared__ float s1c[BB], s2c[BB];
    __shared__ float Af[SPB], Bf[SPB];

    if (t < BB) {
        const float* cmp = cluster_map + t * KCL;
        float best = cmp[0];
        int   bi   = 0;
        for (int k = 1; k < KCL; ++k) {
            float v = cmp[k];
            if (v > best) { best = v; bi = k; }
        }
        cid[t] = bi;
        s1c[t] = s1g[t * CC + c];
        s2c[t] = s2g[t * CC + c];
    }
    __syncthreads();

    if (t < SPB) {
        const int b = bbase + t;
        const int k = cid[b];

        // cluster sums over samples in cluster k, channel c (double, in b-order
        // -> matches the verified stats_kernel numerics)
        double cs1 = 0.0, cs2 = 0.0;
        int cnt = 0;
        for (int b2 = 0; b2 < BB; ++b2) {
            if (cid[b2] == k) { cs1 += (double)s1c[b2]; cs2 += (double)s2c[b2]; ++cnt; }
        }
        double nk = fmax((double)cnt * (double)NSP, 1.0);
        double cm = cs1 / nk;
        double cv = (cs2 - nk * cm * cm) / fmax(nk - 1.0, 1.0);
        float  cmu  = (float)cm;
        float  cstd = sqrtf((float)cv + 1e-6f);

        float sm   = s1c[b] * (1.0f / NSP);
        float sv   = (s2c[b] - (float)NSP * sm * sm) * (1.0f / (NSP - 1));
        float sstd = sqrtf(sv + 1e-6f);

        float l       = lmda[b];
        float mu_mix  = sm   * l + cmu  * (1.0f - l);
        float std_mix = sstd * l + cstd * (1.0f - l);
        float a       = std_mix / sstd;
        Af[t] = a;
        Bf[t] = mu_mix - sm * a;
    }
    __syncthreads();

    // ---- Phase 3: apply my 4 slices ----
    for (int sb = 0; sb < SPB; ++sb) {
        const int b  = bbase + sb;
        const float a  = Af[sb];
        const float bi = Bf[sb];
        const size_t base = (size_t)(b * CC + c) * NSP4;
        for (int i = t; i < NSP4; i += 256) {
            f32x4 v = x[base + i];
            f32x4 o;
            o.x = fmaf(v.x, a, bi);
            o.y = fmaf(v.y, a, bi);
            o.z = fmaf(v.z, a, bi);
            o.w = fmaf(v.w, a, bi);
            __builtin_nontemporal_store(o, &out[base + i]);
        }
    }
}

// ---------------- Fallback path (the verified 3-kernel pipeline) ----------------
__global__ __launch_bounds__(256) void reduce_kernel(
    const f32x4* __restrict__ x, float* __restrict__ s1, float* __restrict__ s2)
{
    const int bc = blockIdx.x;
    const int t  = threadIdx.x;
    const f32x4* p = x + (size_t)bc * NSP4;

    float a1 = 0.0f, a2 = 0.0f;
    for (int i = t; i < NSP4; i += 256) {
        f32x4 v = p[i];
        a1 += v.x + v.y + v.z + v.w;
        a2 += v.x * v.x + v.y * v.y + v.z * v.z + v.w * v.w;
    }
    for (int off = 32; off > 0; off >>= 1) {
        a1 += __shfl_down(a1, off, 64);
        a2 += __shfl_down(a2, off, 64);
    }
    __shared__ float w1[4], w2[4];
    const int wid = t >> 6;
    if ((t & 63) == 0) { w1[wid] = a1; w2[wid] = a2; }
    __syncthreads();
    if (t == 0) {
        s1[bc] = (w1[0] + w1[1]) + (w1[2] + w1[3]);
        s2[bc] = (w2[0] + w2[1]) + (w2[2] + w2[3]);
    }
}

__global__ __launch_bounds__(256) void stats_kernel(
    const float* __restrict__ s1, const float* __restrict__ s2,
    const float* __restrict__ cluster_map, const float* __restrict__ lmda,
    float* __restrict__ A, float* __restrict__ Bias)
{
    const int t = threadIdx.x;

    __shared__ int    cid[BB];
    __shared__ float  counts[KCL];
    __shared__ double cs1[KCL * CC];
    __shared__ double cs2[KCL * CC];

    if (t < BB) {
        float best = cluster_map[t * KCL];
        int   bi   = 0;
        for (int k = 1; k < KCL; k++) {
            float v = cluster_map[t * KCL + k];
            if (v > best) { best = v; bi = k; }
        }
        cid[t] = bi;
    }
    __syncthreads();

    if (t < KCL) {
        int cnt = 0;
        for (int b = 0; b < BB; b++) if (cid[b] == t) cnt++;
        counts[t] = (float)cnt;
    }
    if (t < CC) {
        for (int k = 0; k < KCL; k++) { cs1[k * CC + t] = 0.0; cs2[k * CC + t] = 0.0; }
        for (int b = 0; b < BB; b++) {
            int k = cid[b];
            cs1[k * CC + t] += (double)s1[b * CC + t];
            cs2[k * CC + t] += (double)s2[b * CC + t];
        }
    }
    __syncthreads();

    for (int i = t; i < BC; i += 256) {
        const int b = i >> 6;
        const int c = i & 63;

        float sm   = s1[i] * (1.0f / NSP);
        float sv   = (s2[i] - (float)NSP * sm * sm) * (1.0f / (NSP - 1));
        float smu  = sm;
        float sstd = sqrtf(sv + 1e-6f);

        int    k   = cid[b];
        double nk  = fmax((double)counts[k] * (double)NSP, 1.0);
        double cm  = cs1[k * CC + c] / nk;
        double cv  = (cs2[k * CC + c] - nk * cm * cm) / fmax(nk - 1.0, 1.0);
        float  cmu  = (float)cm;
        float  cstd = sqrtf((float)cv + 1e-6f);

        float l = lmda[b];
        float mu_mix  = smu  * l + cmu  * (1.0f - l);
        float std_mix = sstd * l + cstd * (1.0f - l);
        float a = std_mix / sstd;
        A[i]    = a;
        Bias[i] = mu_mix - smu * a;
    }
}

__global__ __launch_bounds__(256) void apply_kernel(
    const f32x4* __restrict__ x, const float* __restrict__ A,
    const float* __restrict__ Bias, f32x4* __restrict__ out)
{
    const int bc = blockIdx.x;
    const int t  = threadIdx.x;
    const float a  = A[bc];
    const float bb = Bias[bc];
    const size_t base = (size_t)bc * NSP4;

    for (int i = t; i < NSP4; i += 256) {
        f32x4 v = x[base + i];
        f32x4 o;
        o.x = fmaf(v.x, a, bb);
        o.y = fmaf(v.y, a, bb);
        o.z = fmaf(v.z, a, bb);
        o.w = fmaf(v.w, a, bb);
        __builtin_nontemporal_store(o, &out[base + i]);
    }
}

extern "C" void kernel_launch(void* const* d_in, const int* in_sizes, int n_in,
                              void* d_out, int out_size, void* d_ws, size_t ws_size,
                              hipStream_t stream)
{
    const f32x4* x4 = (const f32x4*)d_in[0];   // [64,64,112,112]
    const float* cm = (const float*)d_in[1];   // [1,64,8]
    const float* lm = (const float*)d_in[2];   // [64,1,1,1]
    f32x4* out4 = (f32x4*)d_out;

    float* s1   = (float*)d_ws;                // 4096 floats
    float* s2   = s1 + BC;                     // 4096 floats
    float* A    = s2 + BC;                     // 4096 floats (fallback only)
    float* Bias = A + BC;                      // 4096 floats (fallback only)

    void* args[] = { (void*)&x4, (void*)&cm, (void*)&lm,
                     (void*)&out4, (void*)&s1, (void*)&s2 };
    hipError_t err = hipLaunchCooperativeKernel(
        (const void*)fused_kernel, dim3(NBLK), dim3(256), args, 0, stream);

    if (err != hipSuccess) {
        // proven 3-kernel fallback
        reduce_kernel<<<BC, 256, 0, stream>>>(x4, s1, s2);
        stats_kernel<<<1, 256, 0, stream>>>(s1, s2, cm, lm, A, Bias);
        apply_kernel<<<BC, 256, 0, stream>>>(x4, A, Bias, out4);
    }
}

// Round 2
// 373.089 us; speedup vs baseline: 1.5197x; 1.5197x over previous
//
#include <hip/hip_runtime.h>

#define BB   64
#define CC   64
#define NSP  12544     // 112*112
#define NSP4 3136      // NSP/4
#define BC   (BB*CC)   // 4096
#define KCL  8
#define NFULL 12       // full unrolled loads per thread (12*256 = 3072)
#define TAILBASE 3072  // remaining 64 f32x4 handled by threads t<64

typedef float f32x4 __attribute__((ext_vector_type(4)));

// ---------------- Kernel 1: per-(b,c) sum and sumsq over H*W ----------------
// One block per (b,c), 256 threads. All 12 slice loads issued up-front into
// registers (static indices -> stays in VGPRs, ~12 loads in flight per wave),
// then accumulated in the ORIGINAL per-thread order (bitwise-same s1/s2 as
// the verified version). Cached loads so x lands in L2/L3 for apply.
__global__ __launch_bounds__(256) void reduce_kernel(
    const f32x4* __restrict__ x, float* __restrict__ s1, float* __restrict__ s2)
{
    const int bc = blockIdx.x;
    const int t  = threadIdx.x;
    const f32x4* p = x + (size_t)bc * NSP4;

    f32x4 v[NFULL];
#pragma unroll
    for (int j = 0; j < NFULL; ++j) v[j] = p[t + j * 256];
    f32x4 vt;
    const bool tail = (t < 64);
    if (tail) vt = p[TAILBASE + t];

    float a1 = 0.0f, a2 = 0.0f;
#pragma unroll
    for (int j = 0; j < NFULL; ++j) {
        a1 += v[j].x + v[j].y + v[j].z + v[j].w;
        a2 += v[j].x * v[j].x + v[j].y * v[j].y + v[j].z * v[j].z + v[j].w * v[j].w;
    }
    if (tail) {
        a1 += vt.x + vt.y + vt.z + vt.w;
        a2 += vt.x * vt.x + vt.y * vt.y + vt.z * vt.z + vt.w * vt.w;
    }

    // 64-lane wave reduction
    for (int off = 32; off > 0; off >>= 1) {
        a1 += __shfl_down(a1, off, 64);
        a2 += __shfl_down(a2, off, 64);
    }

    __shared__ float w1[4], w2[4];
    const int wid = t >> 6;
    if ((t & 63) == 0) { w1[wid] = a1; w2[wid] = a2; }
    __syncthreads();
    if (t == 0) {
        s1[bc] = (w1[0] + w1[1]) + (w1[2] + w1[3]);
        s2[bc] = (w2[0] + w2[1]) + (w2[2] + w2[3]);
    }
}

// ---------------- Kernel 2: stats (per-block, redundant) + apply ----------------
// One block per (b,c). All 12 x-loads are issued FIRST; the per-block stats
// computation (argmax + double-precision cluster sums for this channel only —
// numerics identical to the verified fused phase 2) runs while those loads are
// in flight, so it costs ~zero wall time. NT stores keep out from polluting L3.
__global__ __launch_bounds__(256) void apply_kernel(
    const f32x4* __restrict__ x,
    const float* __restrict__ s1, const float* __restrict__ s2,
    const float* __restrict__ cluster_map,   // [B,K]
    const float* __restrict__ lmda,          // [B]
    f32x4* __restrict__ out)
{
    const int bc = blockIdx.x;
    const int b  = bc >> 6;
    const int c  = bc & 63;
    const int t  = threadIdx.x;
    const size_t base = (size_t)bc * NSP4;

    // ---- issue all x loads up-front ----
    f32x4 v[NFULL];
#pragma unroll
    for (int j = 0; j < NFULL; ++j) v[j] = x[base + t + j * 256];
    f32x4 vt;
    const bool tail = (t < 64);
    if (tail) vt = x[base + TAILBASE + t];

    // ---- stats for this (b,c), overlapped with the loads above ----
    __shared__ int   cid[BB];
    __shared__ float s1c[BB], s2c[BB];
    __shared__ float sA, sBias;

    if (t < BB) {
        const float* cmp = cluster_map + t * KCL;
        float best = cmp[0];
        int   bi   = 0;
        for (int k = 1; k < KCL; ++k) {
            float q = cmp[k];
            if (q > best) { best = q; bi = k; }
        }
        cid[t] = bi;
        s1c[t] = s1[t * CC + c];
        s2c[t] = s2[t * CC + c];
    }
    __syncthreads();

    if (t == 0) {
        const int k = cid[b];
        // cluster sums over samples in cluster k, channel c (double, b-order:
        // matches the verified stats numerics)
        double cs1 = 0.0, cs2 = 0.0;
        int cnt = 0;
        for (int b2 = 0; b2 < BB; ++b2) {
            if (cid[b2] == k) { cs1 += (double)s1c[b2]; cs2 += (double)s2c[b2]; ++cnt; }
        }
        double nk = fmax((double)cnt * (double)NSP, 1.0);
        double cm = cs1 / nk;
        double cv = (cs2 - nk * cm * cm) / fmax(nk - 1.0, 1.0);
        float  cmu  = (float)cm;
        float  cstd = sqrtf((float)cv + 1e-6f);

        float sm   = s1c[b] * (1.0f / NSP);
        float sv   = (s2c[b] - (float)NSP * sm * sm) * (1.0f / (NSP - 1));
        float sstd = sqrtf(sv + 1e-6f);

        float l       = lmda[b];
        float mu_mix  = sm   * l + cmu  * (1.0f - l);
        float std_mix = sstd * l + cstd * (1.0f - l);
        float a       = std_mix / sstd;
        sA    = a;
        sBias = mu_mix - sm * a;
    }
    __syncthreads();

    const float a  = sA;
    const float bi = sBias;

    // ---- transform + NT store ----
#pragma unroll
    for (int j = 0; j < NFULL; ++j) {
        f32x4 o;
        o.x = fmaf(v[j].x, a, bi);
        o.y = fmaf(v[j].y, a, bi);
        o.z = fmaf(v[j].z, a, bi);
        o.w = fmaf(v[j].w, a, bi);
        __builtin_nontemporal_store(o, &out[base + t + j * 256]);
    }
    if (tail) {
        f32x4 o;
        o.x = fmaf(vt.x, a, bi);
        o.y = fmaf(vt.y, a, bi);
        o.z = fmaf(vt.z, a, bi);
        o.w = fmaf(vt.w, a, bi);
        __builtin_nontemporal_store(o, &out[base + TAILBASE + t]);
    }
}

extern "C" void kernel_launch(void* const* d_in, const int* in_sizes, int n_in,
                              void* d_out, int out_size, void* d_ws, size_t ws_size,
                              hipStream_t stream)
{
    const f32x4* x4 = (const f32x4*)d_in[0];   // [64,64,112,112]
    const float* cm = (const float*)d_in[1];   // [1,64,8]
    const float* lm = (const float*)d_in[2];   // [64,1,1,1]
    f32x4* out4 = (f32x4*)d_out;

    float* s1 = (float*)d_ws;                  // 4096 floats
    float* s2 = s1 + BC;                       // 4096 floats

    reduce_kernel<<<BC, 256, 0, stream>>>(x4, s1, s2);
    apply_kernel<<<BC, 256, 0, stream>>>(x4, s1, s2, cm, lm, out4);
}

// Round 3
// 372.729 us; speedup vs baseline: 1.5212x; 1.0010x over previous
//
#include <hip/hip_runtime.h>

#define BB   64
#define CC   64
#define NSP  12544     // 112*112
#define NSP4 3136      // NSP/4
#define BC   (BB*CC)   // 4096
#define KCL  8
#define NFULL 12       // full unrolled loads per thread (12*256 = 3072)
#define TAILBASE 3072  // remaining 64 f32x4 handled by threads t<64

typedef float f32x4 __attribute__((ext_vector_type(4)));

// ---------------- Kernel 1: per-(b,c) sum and sumsq over H*W ----------------
// One block per (b,c), 256 threads, 12 loads in flight, accumulation order
// identical to the verified version (bitwise-same s1/s2). Cached loads so x
// lands in L3 for the apply pass.
__global__ __launch_bounds__(256) void reduce_kernel(
    const f32x4* __restrict__ x, float* __restrict__ s1, float* __restrict__ s2)
{
    const int bc = blockIdx.x;
    const int t  = threadIdx.x;
    const f32x4* p = x + (size_t)bc * NSP4;

    f32x4 v[NFULL];
#pragma unroll
    for (int j = 0; j < NFULL; ++j) v[j] = p[t + j * 256];
    f32x4 vt;
    const bool tail = (t < 64);
    if (tail) vt = p[TAILBASE + t];

    float a1 = 0.0f, a2 = 0.0f;
#pragma unroll
    for (int j = 0; j < NFULL; ++j) {
        a1 += v[j].x + v[j].y + v[j].z + v[j].w;
        a2 += v[j].x * v[j].x + v[j].y * v[j].y + v[j].z * v[j].z + v[j].w * v[j].w;
    }
    if (tail) {
        a1 += vt.x + vt.y + vt.z + vt.w;
        a2 += vt.x * vt.x + vt.y * vt.y + vt.z * vt.z + vt.w * vt.w;
    }

    // 64-lane wave reduction
    for (int off = 32; off > 0; off >>= 1) {
        a1 += __shfl_down(a1, off, 64);
        a2 += __shfl_down(a2, off, 64);
    }

    __shared__ float w1[4], w2[4];
    const int wid = t >> 6;
    if ((t & 63) == 0) { w1[wid] = a1; w2[wid] = a2; }
    __syncthreads();
    if (t == 0) {
        s1[bc] = (w1[0] + w1[1]) + (w1[2] + w1[3]);
        s2[bc] = (w2[0] + w2[1]) + (w2[2] + w2[3]);
    }
}

// ---------------- Kernel 2: stats (per-block, redundant) + apply ----------------
// REVERSE block order: reduce read x slices 0..4095 ascending, so L3 holds the
// TAIL of x hottest. Apply therefore processes slices 4095..0 descending — its
// first reads are the hottest L3 lines, converting the sequential re-scan from
// mostly-miss to mostly-hit. Blocks are independent -> pure renaming, no
// numerical change. x loads issued first; stats overlap them; NT stores keep
// out from evicting the not-yet-read portion of x.
__global__ __launch_bounds__(256) void apply_kernel(
    const f32x4* __restrict__ x,
    const float* __restrict__ s1, const float* __restrict__ s2,
    const float* __restrict__ cluster_map,   // [B,K]
    const float* __restrict__ lmda,          // [B]
    f32x4* __restrict__ out)
{
    const int bc = (BC - 1) - blockIdx.x;    // reverse traversal
    const int b  = bc >> 6;
    const int c  = bc & 63;
    const int t  = threadIdx.x;
    const size_t base = (size_t)bc * NSP4;

    // ---- issue all x loads up-front ----
    f32x4 v[NFULL];
#pragma unroll
    for (int j = 0; j < NFULL; ++j) v[j] = x[base + t + j * 256];
    f32x4 vt;
    const bool tail = (t < 64);
    if (tail) vt = x[base + TAILBASE + t];

    // ---- stats for this (b,c), overlapped with the loads above ----
    __shared__ int   cid[BB];
    __shared__ float s1c[BB], s2c[BB];
    __shared__ float sA, sBias;

    if (t < BB) {
        const float* cmp = cluster_map + t * KCL;
        float best = cmp[0];
        int   bi   = 0;
        for (int k = 1; k < KCL; ++k) {
            float q = cmp[k];
            if (q > best) { best = q; bi = k; }
        }
        cid[t] = bi;
        s1c[t] = s1[t * CC + c];
        s2c[t] = s2[t * CC + c];
    }
    __syncthreads();

    if (t == 0) {
        const int k = cid[b];
        // cluster sums over samples in cluster k, channel c (double, b-order:
        // matches the verified stats numerics)
        double cs1 = 0.0, cs2 = 0.0;
        int cnt = 0;
        for (int b2 = 0; b2 < BB; ++b2) {
            if (cid[b2] == k) { cs1 += (double)s1c[b2]; cs2 += (double)s2c[b2]; ++cnt; }
        }
        double nk = fmax((double)cnt * (double)NSP, 1.0);
        double cm = cs1 / nk;
        double cv = (cs2 - nk * cm * cm) / fmax(nk - 1.0, 1.0);
        float  cmu  = (float)cm;
        float  cstd = sqrtf((float)cv + 1e-6f);

        float sm   = s1c[b] * (1.0f / NSP);
        float sv   = (s2c[b] - (float)NSP * sm * sm) * (1.0f / (NSP - 1));
        float sstd = sqrtf(sv + 1e-6f);

        float l       = lmda[b];
        float mu_mix  = sm   * l + cmu  * (1.0f - l);
        float std_mix = sstd * l + cstd * (1.0f - l);
        float a       = std_mix / sstd;
        sA    = a;
        sBias = mu_mix - sm * a;
    }
    __syncthreads();

    const float a  = sA;
    const float bi = sBias;

    // ---- transform + NT store ----
#pragma unroll
    for (int j = 0; j < NFULL; ++j) {
        f32x4 o;
        o.x = fmaf(v[j].x, a, bi);
        o.y = fmaf(v[j].y, a, bi);
        o.z = fmaf(v[j].z, a, bi);
        o.w = fmaf(v[j].w, a, bi);
        __builtin_nontemporal_store(o, &out[base + t + j * 256]);
    }
    if (tail) {
        f32x4 o;
        o.x = fmaf(vt.x, a, bi);
        o.y = fmaf(vt.y, a, bi);
        o.z = fmaf(vt.z, a, bi);
        o.w = fmaf(vt.w, a, bi);
        __builtin_nontemporal_store(o, &out[base + TAILBASE + t]);
    }
}

extern "C" void kernel_launch(void* const* d_in, const int* in_sizes, int n_in,
                              void* d_out, int out_size, void* d_ws, size_t ws_size,
                              hipStream_t stream)
{
    const f32x4* x4 = (const f32x4*)d_in[0];   // [64,64,112,112]
    const float* cm = (const float*)d_in[1];   // [1,64,8]
    const float* lm = (const float*)d_in[2];   // [64,1,1,1]
    f32x4* out4 = (f32x4*)d_out;

    float* s1 = (float*)d_ws;                  // 4096 floats
    float* s2 = s1 + BC;                       // 4096 floats

    reduce_kernel<<<BC, 256, 0, stream>>>(x4, s1, s2);
    apply_kernel<<<BC, 256, 0, stream>>>(x4, s1, s2, cm, lm, out4);
}